// Round 4
// baseline (232.566 us; speedup 1.0000x reference)
//
#include <hip/hip_runtime.h>

#define DIM 4096
#define HAD_SCALE 0.015625f  // 1/sqrt(4096) = 1/64

// DPP quad_perm lane shuffle (VALU pipe). 0xB1 = lane^1, 0x4E = lane^2.
template <int CTRL>
__device__ __forceinline__ float qperm(float v) {
    return __int_as_float(
        __builtin_amdgcn_mov_dpp(__float_as_int(v), CTRL, 0xF, 0xF, false));
}

// ds_swizzle bit-mode lane xor (LDS pipe, no LDS storage). offset encoding:
// (xor<<10)|(or<<5)|and, and=0x1F. xor4=0x101F, xor8=0x201F, xor16=0x401F.
template <int OFS>
__device__ __forceinline__ float lswz(float v) {
    return __int_as_float(
        __builtin_amdgcn_ds_swizzle(__float_as_int(v), OFS));
}

// Cross-lane butterfly: new = own*sign + partner -> a+b on the bit==0 lane,
// a-b on the bit==1 lane. fma with sign=+-1 is bit-exact vs add/sub.

// ONE WAVE PER ROW: 64 lanes x 64 floats = 4096. 256-thread blocks hold 4
// fully independent waves (4 rows) -> NO barriers, NO LDS storage.
// Layout (fixed): j = e + 4*lane + 256*g   (e = float4 elem, g = reg group).
// Bit schedule (12 j-bits, each exactly once):
//   in-register fwht        : bits {0,1}   (e)  - per-float4, right after load
//   DPP quad_perm xor1/xor2 : bits {2,3}   (lane bits 0,1)
//   ds_swizzle xor4/8/16    : bits {4,5,6} (lane bits 2,3,4)
//   shfl_xor 32             : bit  {7}     (lane bit 5)
//   in-register fwht        : bits {8..11} (g)  - 4 stages over the 16 groups
// Memory: 16 outstanding global_load_dwordx4 per wave (16 KiB in flight,
// 4x the old kernel) and per-group compute overlaps the load tail.
__global__ __launch_bounds__(256) void fwht_kernel(const float* __restrict__ x,
                                                   float* __restrict__ y) {
    const int t = threadIdx.x;
    const int lane = t & 63;
    const int w = t >> 6;
    const size_t row = (size_t)blockIdx.x * 4 + w;
    const float4* __restrict__ x4 = (const float4*)(x + row * DIM);
    float4* __restrict__ y4 = (float4*)(y + row * DIM);

    float r[64];

    // ---- Issue ALL 16 loads up front: contiguous 1 KiB per wave instr,
    // 16 KiB outstanding per wave.
#pragma unroll
    for (int g = 0; g < 16; g++) {
        float4 v = x4[g * 64 + lane];
        r[4 * g + 0] = v.x;
        r[4 * g + 1] = v.y;
        r[4 * g + 2] = v.z;
        r[4 * g + 3] = v.w;
    }

    const float sA = (lane & 1)  ? -1.f : 1.f;
    const float sB = (lane & 2)  ? -1.f : 1.f;
    const float sC = (lane & 4)  ? -1.f : 1.f;
    const float sD = (lane & 8)  ? -1.f : 1.f;
    const float sE = (lane & 16) ? -1.f : 1.f;
    const float sF = (lane & 32) ? -1.f : 1.f;

    // ---- Per-group: e-bit fwht (bits 0,1) + all 6 lane-bit butterflies.
    // Each group g depends only on its own load -> compute overlaps the
    // remaining loads' latency (compiler waits vmcnt per use).
#pragma unroll
    for (int g = 0; g < 16; g++) {
        {   // bits {0,1}: 2x2 fwht within the float4
            float a = r[4 * g + 0], b = r[4 * g + 1];
            float c = r[4 * g + 2], d = r[4 * g + 3];
            float ab0 = a + b, ab1 = a - b;   // bit0
            float cd0 = c + d, cd1 = c - d;
            r[4 * g + 0] = ab0 + cd0;         // bit1
            r[4 * g + 1] = ab1 + cd1;
            r[4 * g + 2] = ab0 - cd0;
            r[4 * g + 3] = ab1 - cd1;
        }
#pragma unroll
        for (int e = 0; e < 4; e++) {   // bits {2..7}: cross-lane chain
            float v = r[4 * g + e];
            v = __builtin_fmaf(v, sA, qperm<0xB1>(v));        // j bit 2
            v = __builtin_fmaf(v, sB, qperm<0x4E>(v));        // j bit 3
            v = __builtin_fmaf(v, sC, lswz<0x101F>(v));       // j bit 4
            v = __builtin_fmaf(v, sD, lswz<0x201F>(v));       // j bit 5
            v = __builtin_fmaf(v, sE, lswz<0x401F>(v));       // j bit 6
            v = __builtin_fmaf(v, sF, __shfl_xor(v, 32, 64)); // j bit 7
            r[4 * g + e] = v;
        }
    }

    // ---- bits {8..11}: fwht over the group index (reg bits 2..5).
    // All-register butterflies, static indices only (no scratch).
#pragma unroll
    for (int s = 4; s < 64; s <<= 1) {
#pragma unroll
        for (int i = 0; i < 64; i++) {
            if ((i & s) == 0) {
                float a = r[i];
                float b = r[i ^ s];
                r[i]     = a + b;   // bit==0 slot: a + b (matches reference)
                r[i ^ s] = a - b;
            }
        }
    }

    // ---- Store: 16x contiguous 1 KiB per wave instruction.
#pragma unroll
    for (int g = 0; g < 16; g++) {
        y4[g * 64 + lane] = make_float4(r[4 * g + 0] * HAD_SCALE,
                                        r[4 * g + 1] * HAD_SCALE,
                                        r[4 * g + 2] * HAD_SCALE,
                                        r[4 * g + 3] * HAD_SCALE);
    }
}

extern "C" void kernel_launch(void* const* d_in, const int* in_sizes, int n_in,
                              void* d_out, int out_size, void* d_ws, size_t ws_size,
                              hipStream_t stream) {
    const float* x = (const float*)d_in[0];
    float* y = (float*)d_out;
    const int n = in_sizes[0];
    const int rows = n / DIM;       // 8192 for (4, 2048, 4096)
    fwht_kernel<<<rows / 4, 256, 0, stream>>>(x, y);
}